// Round 2
// baseline (7346.663 us; speedup 1.0000x reference)
//
#include <hip/hip_runtime.h>
#include <hip/hip_bf16.h>

// Problem constants (SelfAttention2D: B=8,C=256,H=W=128,WS=16,heads=8)
#define BD    8
#define CD    256
#define HD_   128
#define WD_   128
#define WSZ   16
#define TT    256      // tokens per window = WS*WS
#define NWIN  512      // B * (H/WS) * (W/WS)
#define NHEADS 8
#define HDIM  32       // CD / NHEADS

typedef __hip_bfloat16 bf16;

__device__ __forceinline__ float b2f(bf16 v) { return __bfloat162float(v); }
__device__ __forceinline__ bf16  f2b(float v) { return __float2bfloat16(v); }

// ---------------------------------------------------------------------------
// Runtime dtype probe: returns 1 if buffers hold fp32, 0 if bf16.
// bf16 N(0,1) data: every u16 has exponent-field in [96,143]  -> sane = 64/64.
// fp32 data read as u16: even words are raw mantissa bits (~uniform exponent)
//   -> sane ~ 38/64.
// ---------------------------------------------------------------------------
__device__ __forceinline__ int probe_fp32(const void* x) {
    const unsigned short* u = (const unsigned short*)x;
    int sane = 0;
    #pragma unroll
    for (int i = 0; i < 64; ++i) {
        int e = (u[i] >> 7) & 0xFF;
        sane += (e >= 96 && e <= 143) ? 1 : 0;
    }
    return (sane < 55) ? 1 : 0;
}

// Mode-aware input load: ALWAYS a single 2-byte read, always in-bounds.
// fp32 mode: read high u16 of the float (== bf16 truncation of the value).
__device__ __forceinline__ float ldm(const void* p, long i, int m) {
    const char* c = (const char*)p;
    const unsigned short* q =
        (const unsigned short*)(c + (m ? ((i << 2) + 2) : (i << 1)));
    unsigned int v = ((unsigned int)(*q)) << 16;
    return __uint_as_float(v);
}

// Mode-aware output store (uniform branch; stores are not speculated).
__device__ __forceinline__ void stm(void* p, long i, int m, float v) {
    if (m) ((float*)p)[i] = v;
    else   ((bf16*)p)[i]  = f2b(v);
}

// ---------------------------------------------------------------------------
// K1: window partition + LayerNorm -> xn[N][T][C] (bf16), stored in d_out
// one block per window, one thread per token
// ---------------------------------------------------------------------------
__global__ __launch_bounds__(256)
void ln_kernel(const void* __restrict__ x, const void* __restrict__ ln_w,
               const void* __restrict__ ln_b, bf16* __restrict__ xn)
{
    const int m = probe_fp32(x);

    __shared__ float lw[CD], lb[CD];
    lw[threadIdx.x] = ldm(ln_w, threadIdx.x, m);
    lb[threadIdx.x] = ldm(ln_b, threadIdx.x, m);
    __syncthreads();

    const int n = blockIdx.x;
    const int t = threadIdx.x;
    const int b = n >> 6, r = n & 63;
    const int h0 = (r >> 3) * WSZ, w0 = (r & 7) * WSZ;
    const int ty = t >> 4, tx = t & 15;
    const long pixbase = (long)b * CD * HD_ * WD_ + (long)(h0 + ty) * WD_ + (w0 + tx);

    float s = 0.f, ss = 0.f;
    for (int c = 0; c < CD; ++c) {
        float v = ldm(x, pixbase + (long)c * (HD_ * WD_), m);
        s += v; ss += v * v;
    }
    const float mean = s * (1.0f / CD);
    const float var  = ss * (1.0f / CD) - mean * mean;
    const float rstd = rsqrtf(fmaxf(var, 0.f) + 1e-5f);

    const long orow = ((long)n * TT + t) * CD;
    for (int c = 0; c < CD; ++c) {
        float v = ldm(x, pixbase + (long)c * (HD_ * WD_), m);
        xn[orow + c] = f2b((v - mean) * rstd * lw[c] + lb[c]);
    }
}

// ---------------------------------------------------------------------------
// K2: per (window, head): QKV projection + online-softmax attention
//   -> ctx[N][T][C] (bf16), head h fills channels [h*32, h*32+32)
// one block per (window, head), one thread per query token
// ---------------------------------------------------------------------------
__global__ __launch_bounds__(256)
void attn_kernel(const void* __restrict__ xprobe, const bf16* __restrict__ xn,
                 const void* __restrict__ w_qkv, const void* __restrict__ b_qkv,
                 bf16* __restrict__ ctx)
{
    const int m = probe_fp32(xprobe);

    const int n = blockIdx.x;   // window
    const int h = blockIdx.y;   // head
    const int t = threadIdx.x;  // token

    __shared__ bf16 w_tile[96][64];        // 12 KB: rows 0-31 Wq, 32-63 Wk, 64-95 Wv
    __shared__ bf16 k_s[TT][HDIM];         // 16 KB
    __shared__ bf16 v_s[TT][HDIM];         // 16 KB

    float aq[HDIM], ak[HDIM], av[HDIM];
    #pragma unroll
    for (int j = 0; j < HDIM; ++j) { aq[j] = 0.f; ak[j] = 0.f; av[j] = 0.f; }

    const long xrow = ((long)n * TT + t) * CD;
    for (int c0 = 0; c0 < CD; c0 += 64) {
        for (int e = threadIdx.x; e < 96 * 64; e += 256) {
            int row = e >> 6, col = e & 63;
            int mat = row >> 5, j = row & 31;
            long src = (long)(mat * CD + h * HDIM + j) * CD + c0 + col;
            w_tile[row][col] = f2b(ldm(w_qkv, src, m));
        }
        __syncthreads();
        for (int cc = 0; cc < 64; ++cc) {
            float xv = b2f(xn[xrow + c0 + cc]);
            #pragma unroll
            for (int j = 0; j < HDIM; ++j) {
                aq[j] += xv * b2f(w_tile[j][cc]);
                ak[j] += xv * b2f(w_tile[32 + j][cc]);
                av[j] += xv * b2f(w_tile[64 + j][cc]);
            }
        }
        __syncthreads();
    }

    const float scale = 0.17677669529663687f;  // 1/sqrt(32)
    #pragma unroll
    for (int j = 0; j < HDIM; ++j) {
        aq[j] = (aq[j] + ldm(b_qkv, h * HDIM + j, m)) * scale;
        ak[j] += ldm(b_qkv, CD + h * HDIM + j, m);
        av[j] += ldm(b_qkv, 2 * CD + h * HDIM + j, m);
        k_s[t][j] = f2b(ak[j]);
        v_s[t][j] = f2b(av[j]);
    }
    __syncthreads();

    // online softmax over 256 keys; q row stays in registers (aq)
    float mx = -1e30f, l = 0.f, o[HDIM];
    #pragma unroll
    for (int j = 0; j < HDIM; ++j) o[j] = 0.f;
    for (int kk = 0; kk < TT; ++kk) {
        float s = 0.f;
        #pragma unroll
        for (int j = 0; j < HDIM; ++j) s += aq[j] * b2f(k_s[kk][j]);
        float mn = fmaxf(mx, s);
        float alpha = __expf(mx - mn);
        float p = __expf(s - mn);
        l = l * alpha + p;
        #pragma unroll
        for (int j = 0; j < HDIM; ++j) o[j] = o[j] * alpha + p * b2f(v_s[kk][j]);
        mx = mn;
    }
    const float inv_l = 1.0f / l;
    const long crow = ((long)n * TT + t) * CD + h * HDIM;
    #pragma unroll
    for (int j = 0; j < HDIM; ++j) ctx[crow + j] = f2b(o[j] * inv_l);
}

// ---------------------------------------------------------------------------
// K3: out projection + bias + residual + window reverse -> out[B][C][H][W]
// one block per window, one thread per token.  Overwrites d_out (which held
// xn) — safe: no K3 block reads xn.
// ---------------------------------------------------------------------------
__global__ __launch_bounds__(256)
void proj_kernel(const bf16* __restrict__ ctx, const void* __restrict__ w_out,
                 const void* __restrict__ b_out, const void* __restrict__ x,
                 void* __restrict__ out)
{
    const int m = probe_fp32(x);

    const int n = blockIdx.x, t = threadIdx.x;
    const int b = n >> 6, r = n & 63;
    const int h0 = (r >> 3) * WSZ, w0 = (r & 7) * WSZ;
    const int ty = t >> 4, tx = t & 15;
    const long pixbase = (long)b * CD * HD_ * WD_ + (long)(h0 + ty) * WD_ + (w0 + tx);

    __shared__ bf16 w_tile[64][64];   // 8 KB
    const long crow = ((long)n * TT + t) * CD;

    for (int d0 = 0; d0 < CD; d0 += 64) {
        float acc[64];
        #pragma unroll
        for (int j = 0; j < 64; ++j) acc[j] = 0.f;
        for (int c0 = 0; c0 < CD; c0 += 64) {
            __syncthreads();
            for (int e = threadIdx.x; e < 64 * 64; e += 256) {
                int row = e >> 6, col = e & 63;
                w_tile[row][col] = f2b(ldm(w_out, (long)(d0 + row) * CD + c0 + col, m));
            }
            __syncthreads();
            for (int cc = 0; cc < 64; ++cc) {
                float cv = b2f(ctx[crow + c0 + cc]);
                #pragma unroll
                for (int j = 0; j < 64; ++j) acc[j] += cv * b2f(w_tile[j][cc]);
            }
        }
        for (int j = 0; j < 64; ++j) {
            int c = d0 + j;
            float resid = ldm(x, pixbase + (long)c * (HD_ * WD_), m);
            float bo    = ldm(b_out, c, m);
            stm(out, pixbase + (long)c * (HD_ * WD_), m, acc[j] + bo + resid);
        }
    }
}

// ---------------------------------------------------------------------------
extern "C" void kernel_launch(void* const* d_in, const int* in_sizes, int n_in,
                              void* d_out, int out_size, void* d_ws, size_t ws_size,
                              hipStream_t stream)
{
    const void* x     = d_in[0];
    const void* ln_w  = d_in[1];
    const void* ln_b  = d_in[2];
    const void* w_qkv = d_in[3];
    const void* b_qkv = d_in[4];
    const void* w_out = d_in[5];
    const void* b_out = d_in[6];

    // xn lives in d_out (>= 67 MB in either dtype; dead before K3 rewrites it)
    bf16* xn  = (bf16*)d_out;
    // ctx is the only d_ws user: 67 MB
    bf16* ctx = (bf16*)d_ws;

    hipLaunchKernelGGL(ln_kernel,   dim3(NWIN),         dim3(256), 0, stream,
                       x, ln_w, ln_b, xn);
    hipLaunchKernelGGL(attn_kernel, dim3(NWIN, NHEADS), dim3(256), 0, stream,
                       x, xn, w_qkv, b_qkv, ctx);
    hipLaunchKernelGGL(proj_kernel, dim3(NWIN),         dim3(256), 0, stream,
                       ctx, w_out, b_out, x, d_out);
}

// Round 3
// 1403.014 us; speedup vs baseline: 5.2363x; 5.2363x over previous
//
#include <hip/hip_runtime.h>
#include <hip/hip_bf16.h>

// SelfAttention2D: B=8, C=256, H=W=128, WS=16, heads=8, hd=32
// Device dtypes (established round 1-2): ALL inputs fp32, output fp32.
#define CD    256
#define HW_   16384        // 128*128
#define WSZ   16
#define TT    256          // tokens per window
#define NWIN  512
#define NHEADS 8
#define HDIM  32

typedef __hip_bfloat16 bf16;
typedef unsigned short ushort_t;
typedef __attribute__((ext_vector_type(8))) short bf16x8;  // MFMA A/B frag (8 bf16)
typedef __attribute__((ext_vector_type(4))) float f32x4;   // MFMA C/D frag

__device__ __forceinline__ float bflo(int two) { return __uint_as_float(((unsigned)two) << 16); }
__device__ __forceinline__ float bfhi(int two) { return __uint_as_float(((unsigned)two) & 0xffff0000u); }
__device__ __forceinline__ ushort_t f2bu(float v) {
    union { bf16 b; ushort_t u; } cv; cv.b = __float2bfloat16(v); return cv.u;
}

// ---------------------------------------------------------------------------
// K0: weights fp32 -> bf16 (w_qkv: 768x256, w_out: 256x256)
// ---------------------------------------------------------------------------
__global__ __launch_bounds__(256)
void convw_kernel(const float* __restrict__ wq, const float* __restrict__ wo,
                  bf16* __restrict__ wqb, bf16* __restrict__ wob)
{
    int i = blockIdx.x * 256 + threadIdx.x;            // grid 1024 -> i < 262144
    if (i < 3 * CD * CD) wqb[i] = __float2bfloat16(wq[i]);
    int j = i - 3 * CD * CD;
    if (j >= 0 && j < CD * CD) wob[j] = __float2bfloat16(wo[j]);
}

// ---------------------------------------------------------------------------
// K1: window partition + LayerNorm -> xn[N*T][C] bf16 (stored in d_out).
// Block = 64 tokens (quarter window), 64 threads (1 wave), thread = token.
// LDS transpose per 64-channel chunk so global writes are 16 B coalesced.
// ---------------------------------------------------------------------------
__global__ __launch_bounds__(64)
void ln_kernel(const float* __restrict__ x, const float* __restrict__ lnw,
               const float* __restrict__ lnb, bf16* __restrict__ xn)
{
    __shared__ bf16 buf[64][72];   // 9 KB; stride 72 -> 16B-aligned rows

    const int blk = blockIdx.x;            // 0..2047
    const int n = blk >> 2, q4 = blk & 3;
    const int t = q4 * 64 + threadIdx.x;   // token in window
    const int b = n >> 6, r = n & 63;
    const int h0 = (r >> 3) * WSZ, w0 = (r & 7) * WSZ;
    const int ty = t >> 4, tx = t & 15;
    const float* px = x + (size_t)b * CD * HW_ + (size_t)(h0 + ty) * 128 + (w0 + tx);

    float s = 0.f, ss = 0.f;
    for (int c = 0; c < CD; ++c) { float v = px[(size_t)c * HW_]; s += v; ss += v * v; }
    const float mean = s * (1.f / CD);
    const float var  = ss * (1.f / CD) - mean * mean;
    const float rstd = rsqrtf(fmaxf(var, 0.f) + 1e-5f);

    const size_t gbase = ((size_t)n * TT + (size_t)q4 * 64) * CD;
    for (int cb = 0; cb < 4; ++cb) {
        __syncthreads();
        #pragma unroll
        for (int c8 = 0; c8 < 8; ++c8) {
            union { int4 q; ushort_t u[8]; } pk;
            #pragma unroll
            for (int j = 0; j < 8; ++j) {
                int c = cb * 64 + c8 * 8 + j;
                float v = px[(size_t)c * HW_];
                pk.u[j] = f2bu((v - mean) * rstd * lnw[c] + lnb[c]);
            }
            *(int4*)&buf[threadIdx.x][c8 * 8] = pk.q;
        }
        __syncthreads();
        for (int sl = threadIdx.x; sl < 512; sl += 64) {
            int row = sl >> 3, ch = sl & 7;
            *(int4*)&xn[gbase + (size_t)row * CD + cb * 64 + ch * 8] =
                *(const int4*)&buf[row][ch * 8];
        }
    }
}

// ---------------------------------------------------------------------------
// K2: per (window, head): MFMA QKV projection (256x96x256) + scalar online-
// softmax attention -> ctx[N*T][C] bf16.  256 threads = 4 waves.
// Wave w computes tokens [64w,64w+64) x all 96 outputs.
// ---------------------------------------------------------------------------
__global__ __launch_bounds__(256, 2)
void attn_kernel(const bf16* __restrict__ xn, const bf16* __restrict__ wqb,
                 const float* __restrict__ bqkv, bf16* __restrict__ ctx)
{
    const int n = blockIdx.x, h = blockIdx.y;
    const int tid = threadIdx.x;
    const int wave = tid >> 6, lane = tid & 63;
    const int l16 = lane & 15, q16 = lane >> 4;

    __shared__ union {
        struct { bf16 xs[256][32]; bf16 ws[96][32]; } st;   // 22 KB staging
        struct { bf16 ks[256][32]; bf16 vs[256][32]; } kv;  // 32 KB K/V
    } u;
    __shared__ bf16 qs[256][32];                            // 16 KB

    f32x4 acc[4][6];
    const f32x4 zero = {0.f, 0.f, 0.f, 0.f};
    #pragma unroll
    for (int mt = 0; mt < 4; ++mt)
        #pragma unroll
        for (int nt = 0; nt < 6; ++nt) acc[mt][nt] = zero;

    const size_t xbase = ((size_t)n * TT + tid) * CD;
    for (int kc = 0; kc < 8; ++kc) {
        __syncthreads();
        {   // stage A: xn rows (64 B each), thread -> row
            const int4* src = (const int4*)(xn + xbase + kc * 32);
            int4* dst = (int4*)&u.st.xs[tid][0];
            #pragma unroll
            for (int i = 0; i < 4; ++i) dst[i] = src[i];
        }
        #pragma unroll
        for (int sl0 = 0; sl0 < 2; ++sl0) {   // stage B: 96 rows x 4 chunks
            int sl = sl0 * 256 + tid;
            if (sl < 384) {
                int row = sl >> 2, ch = sl & 3;
                int mat = row >> 5, j = row & 31;
                *(int4*)&u.st.ws[row][ch * 8] =
                    *(const int4*)(wqb + ((size_t)(mat * CD + h * HDIM + j)) * CD
                                   + (size_t)kc * 32 + ch * 8);
            }
        }
        __syncthreads();
        bf16x8 af[4], bg[6];
        #pragma unroll
        for (int mt = 0; mt < 4; ++mt)
            af[mt] = *(const bf16x8*)&u.st.xs[wave * 64 + mt * 16 + l16][q16 * 8];
        #pragma unroll
        for (int nt = 0; nt < 6; ++nt)
            bg[nt] = *(const bf16x8*)&u.st.ws[nt * 16 + l16][q16 * 8];
        #pragma unroll
        for (int mt = 0; mt < 4; ++mt)
            #pragma unroll
            for (int nt = 0; nt < 6; ++nt)
                acc[mt][nt] = __builtin_amdgcn_mfma_f32_16x16x32_bf16(
                                  af[mt], bg[nt], acc[mt][nt], 0, 0, 0);
    }
    __syncthreads();   // staging dead; union flips to K/V

    // epilogue: bias (+ q-scale), scatter C-frags into qs/ks/vs LDS
    const float qscale = 0.17677669529663687f;   // 1/sqrt(32)
    #pragma unroll
    for (int nt = 0; nt < 6; ++nt) {
        const int mat = nt >> 1;                  // 0=q 1=k 2=v (uniform per nt)
        const int j = ((nt & 1) << 4) | l16;      // 0..31
        const float bias = bqkv[mat * CD + h * HDIM + j];
        #pragma unroll
        for (int mt = 0; mt < 4; ++mt)
            #pragma unroll
            for (int rr = 0; rr < 4; ++rr) {
                int tok = wave * 64 + mt * 16 + q16 * 4 + rr;
                float v = acc[mt][nt][rr] + bias;
                if (mat == 0)      qs[tok][j]      = __float2bfloat16(v * qscale);
                else if (mat == 1) u.kv.ks[tok][j] = __float2bfloat16(v);
                else               u.kv.vs[tok][j] = __float2bfloat16(v);
            }
    }
    __syncthreads();

    // scalar online softmax, thread = query token; K/V rows broadcast from LDS
    float aq[32];
    #pragma unroll
    for (int c8 = 0; c8 < 4; ++c8) {
        int4 qv = *(const int4*)&qs[tid][c8 * 8];
        const int* pi = (const int*)&qv;
        #pragma unroll
        for (int w2 = 0; w2 < 4; ++w2) {
            aq[c8 * 8 + w2 * 2]     = bflo(pi[w2]);
            aq[c8 * 8 + w2 * 2 + 1] = bfhi(pi[w2]);
        }
    }
    float mx = -1e30f, l = 0.f, o[32];
    #pragma unroll
    for (int j = 0; j < 32; ++j) o[j] = 0.f;
    for (int kk = 0; kk < TT; ++kk) {
        float s = 0.f;
        {
            const int4* kr = (const int4*)&u.kv.ks[kk][0];
            #pragma unroll
            for (int c8 = 0; c8 < 4; ++c8) {
                int4 k4 = kr[c8];
                const int* pi = (const int*)&k4;
                #pragma unroll
                for (int w2 = 0; w2 < 4; ++w2)
                    s += aq[c8 * 8 + w2 * 2] * bflo(pi[w2])
                       + aq[c8 * 8 + w2 * 2 + 1] * bfhi(pi[w2]);
            }
        }
        if (s > mx) {          // rare (record maxima): rescale path
            float alpha = __expf(mx - s);
            l *= alpha;
            #pragma unroll
            for (int j = 0; j < 32; ++j) o[j] *= alpha;
            mx = s;
        }
        float p = __expf(s - mx);
        l += p;
        {
            const int4* vr = (const int4*)&u.kv.vs[kk][0];
            #pragma unroll
            for (int c8 = 0; c8 < 4; ++c8) {
                int4 v4 = vr[c8];
                const int* pi = (const int*)&v4;
                #pragma unroll
                for (int w2 = 0; w2 < 4; ++w2) {
                    o[c8 * 8 + w2 * 2]     += p * bflo(pi[w2]);
                    o[c8 * 8 + w2 * 2 + 1] += p * bfhi(pi[w2]);
                }
            }
        }
    }
    const float inv_l = 1.f / l;
    const size_t cbase = ((size_t)n * TT + tid) * CD + h * HDIM;
    #pragma unroll
    for (int c8 = 0; c8 < 4; ++c8) {
        union { int4 q; ushort_t u[8]; } pk;
        #pragma unroll
        for (int j = 0; j < 8; ++j) pk.u[j] = f2bu(o[c8 * 8 + j] * inv_l);
        *(int4*)(ctx + cbase + c8 * 8) = pk.q;
    }
}

// ---------------------------------------------------------------------------
// K3: out-projection MFMA GEMM (131072 x 256 x 256) + bias + residual +
// window reverse -> out fp32 [B][C][H][W].  128x128 tile, BK=64.
// ---------------------------------------------------------------------------
__global__ __launch_bounds__(256, 2)
void proj_kernel(const bf16* __restrict__ ctx, const bf16* __restrict__ wob,
                 const float* __restrict__ bout, const float* __restrict__ x,
                 float* __restrict__ out)
{
    const int mb = blockIdx.x, nb = blockIdx.y;
    const int tid = threadIdx.x;
    const int wave = tid >> 6, lane = tid & 63;
    const int l16 = lane & 15, q16 = lane >> 4;
    const int rowbase = (wave >> 1) * 64, colbase = (wave & 1) * 64;

    __shared__ union {
        struct { bf16 a[128][64]; bf16 b[128][64]; } st;   // 32 KB staging
        bf16 c[128][129];                                   // 33 KB epilogue
    } u;

    f32x4 acc[4][4];
    const f32x4 zero = {0.f, 0.f, 0.f, 0.f};
    #pragma unroll
    for (int mt = 0; mt < 4; ++mt)
        #pragma unroll
        for (int nt = 0; nt < 4; ++nt) acc[mt][nt] = zero;

    const size_t m0 = (size_t)mb * 128;
    for (int kc = 0; kc < 4; ++kc) {
        __syncthreads();
        #pragma unroll
        for (int p = 0; p < 4; ++p) {
            int sl = p * 256 + tid;          // 1024 chunk-slots per operand
            int row = sl >> 3, ch = sl & 7;
            *(int4*)&u.st.a[row][ch * 8] =
                *(const int4*)(ctx + (m0 + row) * CD + kc * 64 + ch * 8);
            *(int4*)&u.st.b[row][ch * 8] =
                *(const int4*)(wob + ((size_t)(nb * 128 + row)) * CD + kc * 64 + ch * 8);
        }
        __syncthreads();
        #pragma unroll
        for (int kt = 0; kt < 2; ++kt) {
            bf16x8 af[4], bg[4];
            #pragma unroll
            for (int mt = 0; mt < 4; ++mt)
                af[mt] = *(const bf16x8*)&u.st.a[rowbase + mt * 16 + l16][kt * 32 + q16 * 8];
            #pragma unroll
            for (int nt = 0; nt < 4; ++nt)
                bg[nt] = *(const bf16x8*)&u.st.b[colbase + nt * 16 + l16][kt * 32 + q16 * 8];
            #pragma unroll
            for (int mt = 0; mt < 4; ++mt)
                #pragma unroll
                for (int nt = 0; nt < 4; ++nt)
                    acc[mt][nt] = __builtin_amdgcn_mfma_f32_16x16x32_bf16(
                                      af[mt], bg[nt], acc[mt][nt], 0, 0, 0);
        }
    }
    __syncthreads();   // staging dead; union flips to C tile

    #pragma unroll
    for (int mt = 0; mt < 4; ++mt)
        #pragma unroll
        for (int nt = 0; nt < 4; ++nt)
            #pragma unroll
            for (int rr = 0; rr < 4; ++rr)
                u.c[rowbase + mt * 16 + q16 * 4 + rr][colbase + nt * 16 + l16] =
                    __float2bfloat16(acc[mt][nt][rr]);
    __syncthreads();

    // transposed readback: bias + residual + window-reverse, float4 stores
    const int dg = tid >> 5;        // 0..7  (channel group)
    const int t0 = (tid & 31) * 4;  // token quad
    for (int p = 0; p < 16; ++p) {
        int d = p * 8 + dg;
        int c = nb * 128 + d;
        size_t g = m0 + t0;
        int n = (int)(g >> 8), wt = (int)(g & 255);
        int b = n >> 6, r = n & 63;
        int h0 = (r >> 3) * WSZ, w0 = (r & 7) * WSZ;
        int ty = wt >> 4, tx = wt & 15;
        size_t addr = (size_t)b * CD * HW_ + (size_t)c * HW_
                    + (size_t)(h0 + ty) * 128 + w0 + tx;
        float bias = bout[c];
        float4 xr = *(const float4*)(x + addr);
        float4 ov;
        ov.x = __bfloat162float(u.c[t0 + 0][d]) + bias + xr.x;
        ov.y = __bfloat162float(u.c[t0 + 1][d]) + bias + xr.y;
        ov.z = __bfloat162float(u.c[t0 + 2][d]) + bias + xr.z;
        ov.w = __bfloat162float(u.c[t0 + 3][d]) + bias + xr.w;
        *(float4*)(out + addr) = ov;
    }
}

// ---------------------------------------------------------------------------
extern "C" void kernel_launch(void* const* d_in, const int* in_sizes, int n_in,
                              void* d_out, int out_size, void* d_ws, size_t ws_size,
                              hipStream_t stream)
{
    const float* x   = (const float*)d_in[0];
    const float* lnw = (const float*)d_in[1];
    const float* lnb = (const float*)d_in[2];
    const float* wq  = (const float*)d_in[3];
    const float* bq  = (const float*)d_in[4];
    const float* wo  = (const float*)d_in[5];
    const float* bo  = (const float*)d_in[6];
    float* out = (float*)d_out;

    // ws: ctx (67 MB) + bf16 weights (0.5 MB).  xn lives in d_out's first
    // 67 MB (bf16; dead before K3 overwrites d_out with fp32 result).
    bf16* ctx = (bf16*)d_ws;
    bf16* wqb = ctx + (size_t)NWIN * TT * CD;
    bf16* wob = wqb + (size_t)3 * CD * CD;
    bf16* xn  = (bf16*)d_out;

    hipLaunchKernelGGL(convw_kernel, dim3(1024),        dim3(256), 0, stream, wq, wo, wqb, wob);
    hipLaunchKernelGGL(ln_kernel,    dim3(2048),        dim3(64),  0, stream, x, lnw, lnb, xn);
    hipLaunchKernelGGL(attn_kernel,  dim3(NWIN, NHEADS), dim3(256), 0, stream, xn, wqb, bq, ctx);
    hipLaunchKernelGGL(proj_kernel,  dim3(1024, 2),     dim3(256), 0, stream, ctx, wob, bo, x, out);
}

// Round 4
// 717.861 us; speedup vs baseline: 10.2341x; 1.9544x over previous
//
#include <hip/hip_runtime.h>
#include <hip/hip_bf16.h>

// SelfAttention2D: B=8, C=256, H=W=128, WS=16, heads=8, hd=32
// Device dtypes (established round 1-2): ALL inputs fp32, output fp32.
#define CD    256
#define HW_   16384        // 128*128
#define WSZ   16
#define TT    256          // tokens per window
#define NWIN  512
#define NHEADS 8
#define HDIM  32

typedef __hip_bfloat16 bf16;
typedef unsigned short ushort_t;
typedef __attribute__((ext_vector_type(8))) short bf16x8;  // MFMA A/B frag (8 bf16)
typedef __attribute__((ext_vector_type(4))) float f32x4;   // MFMA C/D frag

__device__ __forceinline__ ushort_t f2bu(float v) {
    union { bf16 b; ushort_t u; } cv; cv.b = __float2bfloat16(v); return cv.u;
}

// ---------------------------------------------------------------------------
// K0: weights fp32 -> bf16 (w_qkv: 768x256, w_out: 256x256)
// ---------------------------------------------------------------------------
__global__ __launch_bounds__(256)
void convw_kernel(const float* __restrict__ wq, const float* __restrict__ wo,
                  bf16* __restrict__ wqb, bf16* __restrict__ wob)
{
    int i = blockIdx.x * 256 + threadIdx.x;
    if (i < 3 * CD * CD) wqb[i] = __float2bfloat16(wq[i]);
    int j = i - 3 * CD * CD;
    if (j >= 0 && j < CD * CD) wob[j] = __float2bfloat16(wo[j]);
}

// ---------------------------------------------------------------------------
// K1: window partition + LayerNorm -> xn[N*T][C] bf16 (stored in d_out).
// ---------------------------------------------------------------------------
__global__ __launch_bounds__(64)
void ln_kernel(const float* __restrict__ x, const float* __restrict__ lnw,
               const float* __restrict__ lnb, bf16* __restrict__ xn)
{
    __shared__ bf16 buf[64][72];

    const int blk = blockIdx.x;            // 0..2047
    const int n = blk >> 2, q4 = blk & 3;
    const int t = q4 * 64 + threadIdx.x;
    const int b = n >> 6, r = n & 63;
    const int h0 = (r >> 3) * WSZ, w0 = (r & 7) * WSZ;
    const int ty = t >> 4, tx = t & 15;
    const float* px = x + (size_t)b * CD * HW_ + (size_t)(h0 + ty) * 128 + (w0 + tx);

    float s = 0.f, ss = 0.f;
    for (int c = 0; c < CD; ++c) { float v = px[(size_t)c * HW_]; s += v; ss += v * v; }
    const float mean = s * (1.f / CD);
    const float var  = ss * (1.f / CD) - mean * mean;
    const float rstd = rsqrtf(fmaxf(var, 0.f) + 1e-5f);

    const size_t gbase = ((size_t)n * TT + (size_t)q4 * 64) * CD;
    for (int cb = 0; cb < 4; ++cb) {
        __syncthreads();
        #pragma unroll
        for (int c8 = 0; c8 < 8; ++c8) {
            union { int4 q; ushort_t u[8]; } pk;
            #pragma unroll
            for (int j = 0; j < 8; ++j) {
                int c = cb * 64 + c8 * 8 + j;
                float v = px[(size_t)c * HW_];
                pk.u[j] = f2bu((v - mean) * rstd * lnw[c] + lnb[c]);
            }
            *(int4*)&buf[threadIdx.x][c8 * 8] = pk.q;
        }
        __syncthreads();
        for (int sl = threadIdx.x; sl < 512; sl += 64) {
            int row = sl >> 3, ch = sl & 7;
            *(int4*)&xn[gbase + (size_t)row * CD + cb * 64 + ch * 8] =
                *(const int4*)&buf[row][ch * 8];
        }
    }
}

// ---------------------------------------------------------------------------
// K2: per (window, head): MFMA QKV projection + MFMA flash attention
//   -> ctx[N*T][C] bf16.  256 threads = 4 waves; wave owns 64 query tokens.
// ---------------------------------------------------------------------------
__global__ __launch_bounds__(256, 2)
void attn_kernel(const bf16* __restrict__ xn, const bf16* __restrict__ wqb,
                 const float* __restrict__ bqkv, bf16* __restrict__ ctx)
{
    const int n = blockIdx.x, h = blockIdx.y;
    const int tid = threadIdx.x;
    const int wave = tid >> 6, lane = tid & 63;
    const int l16 = lane & 15, q16 = lane >> 4;

    __shared__ union {
        struct { bf16 xs[256][32]; bf16 ws[96][32]; } st;  // 22 KB QKV staging
        bf16 qp[256][40];                                  // 20 KB: Q stage, then P
    } u;
    __shared__ bf16 ks[256][40];     // 20 KB   K rows (pad 40: 2-way, free)
    __shared__ bf16 vst[32][264];    // 16.5 KB V^T (pad 264: 2-way, free)

    // ---------------- phase 1: QKV projection (256 x 96 x 256) --------------
    f32x4 acc[4][6];
    const f32x4 zero = {0.f, 0.f, 0.f, 0.f};
    #pragma unroll
    for (int mt = 0; mt < 4; ++mt)
        #pragma unroll
        for (int nt = 0; nt < 6; ++nt) acc[mt][nt] = zero;

    const size_t xbase = ((size_t)n * TT + tid) * CD;
    for (int kc = 0; kc < 8; ++kc) {
        __syncthreads();
        {
            const int4* src = (const int4*)(xn + xbase + kc * 32);
            int4* dst = (int4*)&u.st.xs[tid][0];
            #pragma unroll
            for (int i = 0; i < 4; ++i) dst[i] = src[i];
        }
        #pragma unroll
        for (int sl0 = 0; sl0 < 2; ++sl0) {
            int sl = sl0 * 256 + tid;
            if (sl < 384) {
                int row = sl >> 2, ch = sl & 3;
                int mat = row >> 5, j = row & 31;
                *(int4*)&u.st.ws[row][ch * 8] =
                    *(const int4*)(wqb + ((size_t)(mat * CD + h * HDIM + j)) * CD
                                   + (size_t)kc * 32 + ch * 8);
            }
        }
        __syncthreads();
        bf16x8 af[4], bg[6];
        #pragma unroll
        for (int mt = 0; mt < 4; ++mt)
            af[mt] = *(const bf16x8*)&u.st.xs[wave * 64 + mt * 16 + l16][q16 * 8];
        #pragma unroll
        for (int nt = 0; nt < 6; ++nt)
            bg[nt] = *(const bf16x8*)&u.st.ws[nt * 16 + l16][q16 * 8];
        #pragma unroll
        for (int mt = 0; mt < 4; ++mt)
            #pragma unroll
            for (int nt = 0; nt < 6; ++nt)
                acc[mt][nt] = __builtin_amdgcn_mfma_f32_16x16x32_bf16(
                                  af[mt], bg[nt], acc[mt][nt], 0, 0, 0);
    }
    __syncthreads();   // all waves done reading st; union flips to qp

    // epilogue: bias (+ q-scale); Q -> qp rows, K -> ks, V -> vst (transposed)
    const float qscale = 0.17677669529663687f;   // 1/sqrt(32)
    #pragma unroll
    for (int nt = 0; nt < 6; ++nt) {
        const int mat = nt >> 1;                  // 0=q 1=k 2=v
        const int j = ((nt & 1) << 4) | l16;      // 0..31
        const float bias = bqkv[mat * CD + h * HDIM + j];
        #pragma unroll
        for (int mt = 0; mt < 4; ++mt)
            #pragma unroll
            for (int rr = 0; rr < 4; ++rr) {
                int tok = wave * 64 + mt * 16 + q16 * 4 + rr;
                float v = acc[mt][nt][rr] + bias;
                if (mat == 0)      u.qp[tok][j] = __float2bfloat16(v * qscale);
                else if (mat == 1) ks[tok][j]   = __float2bfloat16(v);
                else               vst[j][tok]  = __float2bfloat16(v);
            }
    }
    __syncthreads();   // ks/vst visible to all waves

    // ---------------- phase 2: flash attention (no barriers) ----------------
    // Q A-frags (own 64 rows) into registers; qp rows then recycled for P.
    bf16x8 aq[4];
    #pragma unroll
    for (int mt = 0; mt < 4; ++mt)
        aq[mt] = *(const bf16x8*)&u.qp[wave * 64 + mt * 16 + l16][q16 * 8];

    f32x4 acc_o[4][2];
    float m_row[4][4], l_row[4][4];
    #pragma unroll
    for (int mt = 0; mt < 4; ++mt) {
        acc_o[mt][0] = zero; acc_o[mt][1] = zero;
        #pragma unroll
        for (int rr = 0; rr < 4; ++rr) { m_row[mt][rr] = -1e30f; l_row[mt][rr] = 0.f; }
    }

    for (int kc = 0; kc < 8; ++kc) {           // 32 keys per chunk
        bf16x8 kb0 = *(const bf16x8*)&ks[kc * 32 + l16][q16 * 8];
        bf16x8 kb1 = *(const bf16x8*)&ks[kc * 32 + 16 + l16][q16 * 8];
        f32x4 sc[4][2];
        #pragma unroll
        for (int mt = 0; mt < 4; ++mt) {
            sc[mt][0] = __builtin_amdgcn_mfma_f32_16x16x32_bf16(aq[mt], kb0, zero, 0, 0, 0);
            sc[mt][1] = __builtin_amdgcn_mfma_f32_16x16x32_bf16(aq[mt], kb1, zero, 0, 0, 0);
        }
        // online softmax on S chunk (C-layout: row=q16*4+rr, col=nt*16+l16)
        #pragma unroll
        for (int mt = 0; mt < 4; ++mt) {
            #pragma unroll
            for (int rr = 0; rr < 4; ++rr) {
                float s0 = sc[mt][0][rr], s1 = sc[mt][1][rr];
                float cm = fmaxf(s0, s1);
                #pragma unroll
                for (int msk = 1; msk < 16; msk <<= 1)
                    cm = fmaxf(cm, __shfl_xor(cm, msk, 16));
                float mo = m_row[mt][rr];
                float mn = fmaxf(mo, cm);
                float al = __expf(mo - mn);
                float p0 = __expf(s0 - mn), p1 = __expf(s1 - mn);
                float pe = p0 + p1;
                #pragma unroll
                for (int msk = 1; msk < 16; msk <<= 1)
                    pe += __shfl_xor(pe, msk, 16);
                l_row[mt][rr] = l_row[mt][rr] * al + pe;
                m_row[mt][rr] = mn;
                acc_o[mt][0][rr] *= al;
                acc_o[mt][1][rr] *= al;
                int row = wave * 64 + mt * 16 + q16 * 4 + rr;
                u.qp[row][l16]      = __float2bfloat16(p0);
                u.qp[row][16 + l16] = __float2bfloat16(p1);
            }
        }
        // PV: A = P (own qp rows, in-wave ordered), B = V^T chunk
        bf16x8 vb0 = *(const bf16x8*)&vst[l16][kc * 32 + q16 * 8];
        bf16x8 vb1 = *(const bf16x8*)&vst[16 + l16][kc * 32 + q16 * 8];
        #pragma unroll
        for (int mt = 0; mt < 4; ++mt) {
            bf16x8 ap = *(const bf16x8*)&u.qp[wave * 64 + mt * 16 + l16][q16 * 8];
            acc_o[mt][0] = __builtin_amdgcn_mfma_f32_16x16x32_bf16(ap, vb0, acc_o[mt][0], 0, 0, 0);
            acc_o[mt][1] = __builtin_amdgcn_mfma_f32_16x16x32_bf16(ap, vb1, acc_o[mt][1], 0, 0, 0);
        }
    }

    // write ctx (C-layout rows = tokens, cols = head dims)
    #pragma unroll
    for (int mt = 0; mt < 4; ++mt)
        #pragma unroll
        for (int rr = 0; rr < 4; ++rr) {
            const float inv_l = 1.f / l_row[mt][rr];
            int tok = wave * 64 + mt * 16 + q16 * 4 + rr;
            size_t base = ((size_t)n * TT + tok) * CD + h * HDIM;
            ctx[base + l16]      = __float2bfloat16(acc_o[mt][0][rr] * inv_l);
            ctx[base + 16 + l16] = __float2bfloat16(acc_o[mt][1][rr] * inv_l);
        }
}

// ---------------------------------------------------------------------------
// K3: out-projection MFMA GEMM (131072 x 256 x 256) + bias + residual +
// window reverse -> out fp32 [B][C][H][W].  128x128 tile, BK=64.
// ---------------------------------------------------------------------------
__global__ __launch_bounds__(256, 2)
void proj_kernel(const bf16* __restrict__ ctx, const bf16* __restrict__ wob,
                 const float* __restrict__ bout, const float* __restrict__ x,
                 float* __restrict__ out)
{
    const int mb = blockIdx.x, nb = blockIdx.y;
    const int tid = threadIdx.x;
    const int wave = tid >> 6, lane = tid & 63;
    const int l16 = lane & 15, q16 = lane >> 4;
    const int rowbase = (wave >> 1) * 64, colbase = (wave & 1) * 64;

    __shared__ union {
        struct { bf16 a[128][64]; bf16 b[128][64]; } st;   // 32 KB staging
        bf16 c[128][129];                                   // 33 KB epilogue
    } u;

    f32x4 acc[4][4];
    const f32x4 zero = {0.f, 0.f, 0.f, 0.f};
    #pragma unroll
    for (int mt = 0; mt < 4; ++mt)
        #pragma unroll
        for (int nt = 0; nt < 4; ++nt) acc[mt][nt] = zero;

    const size_t m0 = (size_t)mb * 128;
    for (int kc = 0; kc < 4; ++kc) {
        __syncthreads();
        #pragma unroll
        for (int p = 0; p < 4; ++p) {
            int sl = p * 256 + tid;
            int row = sl >> 3, ch = sl & 7;
            *(int4*)&u.st.a[row][ch * 8] =
                *(const int4*)(ctx + (m0 + row) * CD + kc * 64 + ch * 8);
            *(int4*)&u.st.b[row][ch * 8] =
                *(const int4*)(wob + ((size_t)(nb * 128 + row)) * CD + kc * 64 + ch * 8);
        }
        __syncthreads();
        #pragma unroll
        for (int kt = 0; kt < 2; ++kt) {
            bf16x8 af[4], bg[4];
            #pragma unroll
            for (int mt = 0; mt < 4; ++mt)
                af[mt] = *(const bf16x8*)&u.st.a[rowbase + mt * 16 + l16][kt * 32 + q16 * 8];
            #pragma unroll
            for (int nt = 0; nt < 4; ++nt)
                bg[nt] = *(const bf16x8*)&u.st.b[colbase + nt * 16 + l16][kt * 32 + q16 * 8];
            #pragma unroll
            for (int mt = 0; mt < 4; ++mt)
                #pragma unroll
                for (int nt = 0; nt < 4; ++nt)
                    acc[mt][nt] = __builtin_amdgcn_mfma_f32_16x16x32_bf16(
                                      af[mt], bg[nt], acc[mt][nt], 0, 0, 0);
        }
    }
    __syncthreads();

    #pragma unroll
    for (int mt = 0; mt < 4; ++mt)
        #pragma unroll
        for (int nt = 0; nt < 4; ++nt)
            #pragma unroll
            for (int rr = 0; rr < 4; ++rr)
                u.c[rowbase + mt * 16 + q16 * 4 + rr][colbase + nt * 16 + l16] =
                    __float2bfloat16(acc[mt][nt][rr]);
    __syncthreads();

    const int dg = tid >> 5;
    const int t0 = (tid & 31) * 4;
    for (int p = 0; p < 16; ++p) {
        int d = p * 8 + dg;
        int c = nb * 128 + d;
        size_t g = m0 + t0;
        int n = (int)(g >> 8), wt = (int)(g & 255);
        int b = n >> 6, r = n & 63;
        int h0 = (r >> 3) * WSZ, w0 = (r & 7) * WSZ;
        int ty = wt >> 4, tx = wt & 15;
        size_t addr = (size_t)b * CD * HW_ + (size_t)c * HW_
                    + (size_t)(h0 + ty) * 128 + w0 + tx;
        float bias = bout[c];
        float4 xr = *(const float4*)(x + addr);
        float4 ov;
        ov.x = __bfloat162float(u.c[t0 + 0][d]) + bias + xr.x;
        ov.y = __bfloat162float(u.c[t0 + 1][d]) + bias + xr.y;
        ov.z = __bfloat162float(u.c[t0 + 2][d]) + bias + xr.z;
        ov.w = __bfloat162float(u.c[t0 + 3][d]) + bias + xr.w;
        *(float4*)(out + addr) = ov;
    }
}

// ---------------------------------------------------------------------------
extern "C" void kernel_launch(void* const* d_in, const int* in_sizes, int n_in,
                              void* d_out, int out_size, void* d_ws, size_t ws_size,
                              hipStream_t stream)
{
    const float* x   = (const float*)d_in[0];
    const float* lnw = (const float*)d_in[1];
    const float* lnb = (const float*)d_in[2];
    const float* wq  = (const float*)d_in[3];
    const float* bq  = (const float*)d_in[4];
    const float* wo  = (const float*)d_in[5];
    const float* bo  = (const float*)d_in[6];
    float* out = (float*)d_out;

    bf16* ctx = (bf16*)d_ws;
    bf16* wqb = ctx + (size_t)NWIN * TT * CD;
    bf16* wob = wqb + (size_t)3 * CD * CD;
    bf16* xn  = (bf16*)d_out;   // dead before proj_kernel overwrites d_out

    hipLaunchKernelGGL(convw_kernel, dim3(1024),         dim3(256), 0, stream, wq, wo, wqb, wob);
    hipLaunchKernelGGL(ln_kernel,    dim3(2048),         dim3(64),  0, stream, x, lnw, lnb, xn);
    hipLaunchKernelGGL(attn_kernel,  dim3(NWIN, NHEADS), dim3(256), 0, stream, xn, wqb, bq, ctx);
    hipLaunchKernelGGL(proj_kernel,  dim3(1024, 2),      dim3(256), 0, stream, ctx, wob, bo, x, out);
}